// Round 6
// baseline (262.195 us; speedup 1.0000x reference)
//
#include <hip/hip_runtime.h>
#include <hip/hip_bf16.h>
#include <math.h>

#define B_ 4
#define N_ 2048
#define C_ 768
#define H_ 12
#define D_ 64
#define SC_LOG2E 0.18033688f   // 0.125 * log2(e), folded into stored Q

typedef __attribute__((ext_vector_type(8))) short bf16x8;
typedef __attribute__((ext_vector_type(4))) float f32x4;

#define MFMA16(A, B, C) __builtin_amdgcn_mfma_f32_16x16x32_bf16(A, B, C, 0, 0, 0)

#if __has_builtin(__builtin_amdgcn_exp2f)
#define EXP2F(x) __builtin_amdgcn_exp2f(x)
#else
#define EXP2F(x) exp2f(x)
#endif

__device__ __forceinline__ ushort f2bf(float f) {
    union { float f; unsigned u; } v; v.f = f;
    unsigned r = v.u + 0x7fffu + ((v.u >> 16) & 1u);   // RNE
    return (ushort)(r >> 16);
}

#if __has_builtin(__builtin_amdgcn_cvt_pk_bf16_f32)
typedef __attribute__((ext_vector_type(2))) __bf16 bf16x2v;
__device__ __forceinline__ unsigned pack_bf2(float a, float b) {
    union { bf16x2v v; unsigned u; } cv;
    cv.v = __builtin_amdgcn_cvt_pk_bf16_f32(a, b);
    return cv.u;
}
#else
__device__ __forceinline__ unsigned pack_bf2(float a, float b) {
    union { __hip_bfloat162 h2; unsigned u; } cv;
    cv.h2 = __float22bfloat162_rn(make_float2(a, b));
    return cv.u;
}
#endif

// async global->LDS, 16B per lane; lds base wave-uniform, lane i -> base+i*16B.
__device__ __forceinline__ void gl_lds16(const ushort* g, ushort* l) {
    __builtin_amdgcn_global_load_lds(
        (const __attribute__((address_space(1))) unsigned*)g,
        (__attribute__((address_space(3))) unsigned*)l, 16, 0, 0);
}

// ---------- convert x (fp32 -> bf16), 8 elems/thread ----------
__global__ __launch_bounds__(256) void cvt_x(const float* __restrict__ x,
                                             ushort* __restrict__ xb) {
    int i = blockIdx.x * 256 + threadIdx.x;
    const float4* p = (const float4*)x + 2 * (size_t)i;
    float4 a = p[0], bq = p[1];
    union { ushort s[8]; uint4 v; } u;
    u.s[0] = f2bf(a.x);  u.s[1] = f2bf(a.y);  u.s[2] = f2bf(a.z);  u.s[3] = f2bf(a.w);
    u.s[4] = f2bf(bq.x); u.s[5] = f2bf(bq.y); u.s[6] = f2bf(bq.z); u.s[7] = f2bf(bq.w);
    *(uint4*)&xb[(size_t)i * 8] = u.v;
}

// ---------- transpose + convert: W[K][N] fp32 -> Wt[N][K] bf16 ----------
__global__ __launch_bounds__(256) void tr_cvt(const float* __restrict__ W,
                                              ushort* __restrict__ Wt, int K, int N) {
    __shared__ float T[32][33];
    int t = threadIdx.x;
    int k0 = blockIdx.y * 32, n0 = blockIdx.x * 32;
    int r = t >> 3, c4 = (t & 7) * 4;
    float4 v = *(const float4*)&W[(size_t)(k0 + r) * N + n0 + c4];
    T[r][c4] = v.x; T[r][c4 + 1] = v.y; T[r][c4 + 2] = v.z; T[r][c4 + 3] = v.w;
    __syncthreads();
    union { ushort s[4]; unsigned long long u; } o;
    o.s[0] = f2bf(T[c4 + 0][r]);
    o.s[1] = f2bf(T[c4 + 1][r]);
    o.s[2] = f2bf(T[c4 + 2][r]);
    o.s[3] = f2bf(T[c4 + 3][r]);
    *(unsigned long long*)&Wt[(size_t)(n0 + r) * K + k0 + c4] = o.u;
}

// ---------- bf16 MFMA GEMM: A[M][K] bf16, Bt[N][K] bf16, +bias ----------
// 128x128 tile, BK=32, 4 waves each 64x64, global_load_lds + XOR swizzle.
// OBF (qkv path): q-zone cols scaled by SC_LOG2E; v-zone cols stored
// TRANSPOSED into Vt[bh][d][N_] (replaces the separate vtrans kernel).
template <bool OBF>
__global__ __launch_bounds__(256) void gemm_bf16(
    const ushort* __restrict__ A, const ushort* __restrict__ Bt,
    const float* __restrict__ bias, void* __restrict__ outp,
    ushort* __restrict__ Vt, int M, int N, int K)
{
    __shared__ ushort Asl[128 * 32];
    __shared__ ushort Bsl[128 * 32];

    const int tid  = threadIdx.x;
    const int lane = tid & 63, w = tid >> 6;
    const int quad = lane >> 4, l16 = lane & 15;
    const int row0 = blockIdx.y * 128, col0 = blockIdx.x * 128;
    const int mh = (w >> 1) * 64, nh = (w & 1) * 64;
    const int sw = (quad ^ (l16 & 3)) * 8;

    f32x4 acc[4][4];
#pragma unroll
    for (int i = 0; i < 4; i++)
#pragma unroll
        for (int j = 0; j < 4; j++) acc[i][j] = (f32x4)0.f;

    for (int k0 = 0; k0 < K; k0 += 32) {
#pragma unroll
        for (int i = 0; i < 2; i++) {
            int c  = i * 256 + w * 64 + lane;
            int rr = c >> 2;
            int cc = (c & 3) ^ (rr & 3);
            int wb = (i * 256 + w * 64) * 8;
            gl_lds16(&A[(size_t)(row0 + rr) * K + k0 + cc * 8], &Asl[wb]);
            gl_lds16(&Bt[(size_t)(col0 + rr) * K + k0 + cc * 8], &Bsl[wb]);
        }
        __syncthreads();
        bf16x8 af[4], bfr[4];
#pragma unroll
        for (int mt = 0; mt < 4; mt++)
            af[mt] = *(const bf16x8*)&Asl[(mh + mt * 16 + l16) * 32 + sw];
#pragma unroll
        for (int nt = 0; nt < 4; nt++)
            bfr[nt] = *(const bf16x8*)&Bsl[(nh + nt * 16 + l16) * 32 + sw];
#pragma unroll
        for (int mt = 0; mt < 4; mt++)
#pragma unroll
            for (int nt = 0; nt < 4; nt++)
                acc[mt][nt] = MFMA16(af[mt], bfr[nt], acc[mt][nt]);
        __syncthreads();
    }

    if (OBF && col0 >= 2 * C_) {
        // V zone: store transposed into Vt[bh][d][N_], 4 tokens per u64
#pragma unroll
        for (int nt = 0; nt < 4; nt++) {
            int col  = col0 + nh + nt * 16 + l16;
            int d    = col & 63;
            int head = (col - 2 * C_) >> 6;
            float bv = bias[col];
#pragma unroll
            for (int mt = 0; mt < 4; mt++) {
                f32x4 v = acc[mt][nt];
                int tok0 = row0 + mh + mt * 16 + quad * 4;
                int bq = tok0 >> 11, n0 = tok0 & (N_ - 1);
                union { ushort us[4]; unsigned long long u; } o;
#pragma unroll
                for (int r = 0; r < 4; r++) o.us[r] = f2bf(v[r] + bv);
                *(unsigned long long*)&Vt[((size_t)(bq * H_ + head) * D_ + d) * N_ + n0] = o.u;
            }
        }
    } else {
        const float scl = (OBF && col0 < C_) ? SC_LOG2E : 1.f;
#pragma unroll
        for (int nt = 0; nt < 4; nt++) {
            int col = col0 + nh + nt * 16 + l16;
            float bv = bias[col];
#pragma unroll
            for (int mt = 0; mt < 4; mt++) {
                f32x4 v = acc[mt][nt];
#pragma unroll
                for (int r = 0; r < 4; r++) {
                    int row = row0 + mh + mt * 16 + quad * 4 + r;
                    if (OBF)
                        ((ushort*)outp)[(size_t)row * N + col] = f2bf((v[r] + bv) * scl);
                    else
                        ((float*)outp)[(size_t)row * N + col] = v[r] + bv;
                }
            }
        }
    }
}

// ---------- MFMA flash attention, fixed-max softmax, dbuf async staging ----
// Q pre-scaled by 0.125*log2e -> p = exp2(s). K (row-major) and V^T staged
// via global_load_lds double buffers; tile loop unrolled x2 so the buffer
// parity is compile-time and LDS addresses are loop-invariant; staging
// pointers advance by constant strides.
__global__ __launch_bounds__(256) void attn_mfma(
    const ushort* __restrict__ qkvb, const ushort* __restrict__ Vt,
    ushort* __restrict__ attnb)
{
    __shared__ ushort Kd[2][64 * 64];     // [key][d], swizzled 16B chunks
    __shared__ ushort Vd[2][64 * 64];     // [d][key], swizzled 16B chunks
    __shared__ ushort Ptl[4 * 32 * 72];   // per-wave P^T [q][key], pad 72

    const int tid  = threadIdx.x;
    const int lane = tid & 63, w = tid >> 6;
    const int quad = lane >> 4, l16 = lane & 15;
    const int bh = blockIdx.y, b = bh / H_, h = bh % H_;
    const int q0 = blockIdx.x * 128 + w * 32;
    const size_t rowbase = (size_t)b * N_;
    const int hoff = h * D_;
    ushort* Ptw = Ptl + w * 32 * 72;
    const f32x4 Z4 = {0.f, 0.f, 0.f, 0.f};

    const ushort* Kg = qkvb + rowbase * (3 * C_) + C_ + hoff;  // + tok*(3C)
    const ushort* Vg = Vt + (size_t)bh * D_ * N_;              // + d*N_ + tok

    // per-lane staging coords (two 16B chunks per buffer per thread)
    int rr0, cc0, rr1, cc1, wb0, wb1;
    {
        int c0 = w * 64 + lane, c1 = 256 + w * 64 + lane;
        rr0 = c0 >> 3; cc0 = (c0 & 7) ^ (rr0 & 7); wb0 = (w * 64) * 8;
        rr1 = c1 >> 3; cc1 = (c1 & 7) ^ (rr1 & 7); wb1 = (256 + w * 64) * 8;
    }
    const ushort* kp0 = Kg + (size_t)rr0 * (3 * C_) + cc0 * 8;
    const ushort* kp1 = Kg + (size_t)rr1 * (3 * C_) + cc1 * 8;
    const ushort* vp0 = Vg + (size_t)rr0 * N_ + cc0 * 8;
    const ushort* vp1 = Vg + (size_t)rr1 * N_ + cc1 * 8;

    // Q fragments in registers (pre-scaled in qkvb)
    bf16x8 Qf[2][2];
#pragma unroll
    for (int qt = 0; qt < 2; qt++)
#pragma unroll
        for (int c = 0; c < 2; c++)
            Qf[qt][c] = *(const bf16x8*)&qkvb[(rowbase + q0 + qt * 16 + l16) * (3 * C_)
                                              + hoff + c * 32 + quad * 8];

    f32x4 oacc[4][2];
#pragma unroll
    for (int dt = 0; dt < 4; dt++)
#pragma unroll
        for (int qt = 0; qt < 2; qt++) oacc[dt][qt] = (f32x4)0.f;
    float lrow[2] = {0.f, 0.f};

    // stage tile 0 into buffer 0; advance pointers to tile 1
    gl_lds16(kp0, &Kd[0][wb0]);
    gl_lds16(vp0, &Vd[0][wb0]);
    gl_lds16(kp1, &Kd[0][wb1]);
    gl_lds16(vp1, &Vd[0][wb1]);
    kp0 += 64 * 3 * C_; kp1 += 64 * 3 * C_; vp0 += 64; vp1 += 64;
    __syncthreads();

#define TILE_BODY(CB, PREFETCH)                                               \
    {                                                                         \
        if (PREFETCH) {                                                       \
            gl_lds16(kp0, &Kd[(CB) ^ 1][wb0]);                                \
            gl_lds16(vp0, &Vd[(CB) ^ 1][wb0]);                                \
            gl_lds16(kp1, &Kd[(CB) ^ 1][wb1]);                                \
            gl_lds16(vp1, &Vd[(CB) ^ 1][wb1]);                                \
        }                                                                     \
        kp0 += 64 * 3 * C_; kp1 += 64 * 3 * C_; vp0 += 64; vp1 += 64;         \
        f32x4 sacc[4][2];                                                     \
        {   /* c = 0: MFMA with zero C operand (no zero-init movs) */         \
            bf16x8 kf[4];                                                     \
            _Pragma("unroll")                                                 \
            for (int kt = 0; kt < 4; kt++)                                    \
                kf[kt] = *(const bf16x8*)&Kd[CB][(kt * 16 + l16) * 64         \
                                               + ((quad) ^ (l16 & 7)) * 8];   \
            _Pragma("unroll")                                                 \
            for (int kt = 0; kt < 4; kt++)                                    \
                _Pragma("unroll")                                             \
                for (int qt = 0; qt < 2; qt++)                                \
                    sacc[kt][qt] = MFMA16(kf[kt], Qf[qt][0], Z4);             \
        }                                                                     \
        {   /* c = 1: accumulate */                                           \
            bf16x8 kf[4];                                                     \
            _Pragma("unroll")                                                 \
            for (int kt = 0; kt < 4; kt++)                                    \
                kf[kt] = *(const bf16x8*)&Kd[CB][(kt * 16 + l16) * 64         \
                                               + ((4 | quad) ^ (l16 & 7)) * 8]; \
            _Pragma("unroll")                                                 \
            for (int kt = 0; kt < 4; kt++)                                    \
                _Pragma("unroll")                                             \
                for (int qt = 0; qt < 2; qt++)                                \
                    sacc[kt][qt] = MFMA16(kf[kt], Qf[qt][1], sacc[kt][qt]);   \
        }                                                                     \
        _Pragma("unroll")                                                     \
        for (int qt = 0; qt < 2; qt++) {                                      \
            float sum = 0.f;                                                  \
            _Pragma("unroll")                                                 \
            for (int kt = 0; kt < 4; kt++) {                                  \
                float p0 = EXP2F(sacc[kt][qt][0]);                            \
                float p1 = EXP2F(sacc[kt][qt][1]);                            \
                float p2 = EXP2F(sacc[kt][qt][2]);                            \
                float p3 = EXP2F(sacc[kt][qt][3]);                            \
                sum += (p0 + p1) + (p2 + p3);                                 \
                uint2 pk;                                                     \
                pk.x = pack_bf2(p0, p1);                                      \
                pk.y = pack_bf2(p2, p3);                                      \
                *(uint2*)&Ptw[(qt * 16 + l16) * 72 + kt * 16 + quad * 4] = pk; \
            }                                                                 \
            lrow[qt] += sum;                                                  \
        }                                                                     \
        _Pragma("unroll")                                                     \
        for (int c = 0; c < 2; c++) {                                         \
            bf16x8 pf[2];                                                     \
            _Pragma("unroll")                                                 \
            for (int qt = 0; qt < 2; qt++)                                    \
                pf[qt] = *(const bf16x8*)&Ptw[(qt * 16 + l16) * 72            \
                                              + c * 32 + quad * 8];           \
            _Pragma("unroll")                                                 \
            for (int dt = 0; dt < 4; dt++) {                                  \
                bf16x8 vf = *(const bf16x8*)&Vd[CB][(dt * 16 + l16) * 64      \
                                   + (((c << 2) | quad) ^ (l16 & 7)) * 8];    \
                _Pragma("unroll")                                             \
                for (int qt = 0; qt < 2; qt++)                                \
                    oacc[dt][qt] = MFMA16(vf, pf[qt], oacc[dt][qt]);          \
            }                                                                 \
        }                                                                     \
        __syncthreads();                                                      \
    }

    for (int tt = 0; tt < 16; tt++) {
        TILE_BODY(0, 1)
        TILE_BODY(1, (tt < 15))
    }
#undef TILE_BODY

    // epilogue: cross-quad l reduce, normalize, write bf16 [B*N][C]
#pragma unroll
    for (int qt = 0; qt < 2; qt++) {
        float s = lrow[qt];
        s += __shfl_xor(s, 16, 64);
        s += __shfl_xor(s, 32, 64);
        float inv = 1.f / s;
        size_t orow = (rowbase + q0 + qt * 16 + l16) * C_ + hoff;
#pragma unroll
        for (int dt = 0; dt < 4; dt++) {
            union { ushort us[4]; unsigned long long u; } o;
#pragma unroll
            for (int r = 0; r < 4; r++) o.us[r] = f2bf(oacc[dt][qt][r] * inv);
            *(unsigned long long*)&attnb[orow + dt * 16 + quad * 4] = o.u;
        }
    }
}

// ---------------- launcher ----------------
extern "C" void kernel_launch(void* const* d_in, const int* in_sizes, int n_in,
                              void* d_out, int out_size, void* d_ws, size_t ws_size,
                              hipStream_t stream)
{
    const float* x     = (const float*)d_in[0];
    const float* Wqkv  = (const float*)d_in[1];
    const float* bqkv  = (const float*)d_in[2];
    const float* Wproj = (const float*)d_in[3];
    const float* bproj = (const float*)d_in[4];

    ushort* xb     = (ushort*)d_ws;                                    // [8192][768]
    ushort* Wqkvt  = xb + (size_t)B_ * N_ * C_;                        // [2304][768]
    ushort* Wprojt = Wqkvt + (size_t)3 * C_ * C_;                      // [768][768]
    ushort* qkvb   = Wprojt + (size_t)C_ * C_;                         // [8192][2304]
    ushort* attnb  = qkvb + (size_t)B_ * N_ * 3 * C_;                  // [8192][768]
    ushort* Vtb    = attnb + (size_t)B_ * N_ * C_;                     // [48][64][2048]

    const int M = B_ * N_;

    cvt_x<<<(M * C_) / (8 * 256), 256, 0, stream>>>(x, xb);
    tr_cvt<<<dim3((3 * C_) / 32, C_ / 32), 256, 0, stream>>>(Wqkv, Wqkvt, C_, 3 * C_);
    tr_cvt<<<dim3(C_ / 32, C_ / 32), 256, 0, stream>>>(Wproj, Wprojt, C_, C_);

    gemm_bf16<true><<<dim3((3 * C_) / 128, M / 128), 256, 0, stream>>>(
        xb, Wqkvt, bqkv, qkvb, Vtb, M, 3 * C_, C_);

    attn_mfma<<<dim3(N_ / 128, B_ * H_), 256, 0, stream>>>(qkvb, Vtb, attnb);

    gemm_bf16<false><<<dim3(C_ / 128, M / 128), 256, 0, stream>>>(
        attnb, Wprojt, bproj, d_out, nullptr, M, C_, C_);
}

// Round 8
// 252.620 us; speedup vs baseline: 1.0379x; 1.0379x over previous
//
#include <hip/hip_runtime.h>
#include <hip/hip_bf16.h>
#include <math.h>

#define B_ 4
#define N_ 2048
#define C_ 768
#define H_ 12
#define D_ 64
#define SC_LOG2E 0.18033688f   // 0.125 * log2(e), folded into stored Q

typedef __attribute__((ext_vector_type(8))) short bf16x8;
typedef __attribute__((ext_vector_type(4))) short bf16x4;
typedef __attribute__((ext_vector_type(4))) float f32x4;

#define MFMA16(A, B, C)  __builtin_amdgcn_mfma_f32_16x16x32_bf16(A, B, C, 0, 0, 0)
#define MFMAK16(A, B, C) __builtin_amdgcn_mfma_f32_16x16x16bf16_1k(A, B, C, 0, 0, 0)

#if __has_builtin(__builtin_amdgcn_exp2f)
#define EXP2F(x) __builtin_amdgcn_exp2f(x)
#else
#define EXP2F(x) exp2f(x)
#endif

__device__ __forceinline__ ushort f2bf(float f) {
    union { float f; unsigned u; } v; v.f = f;
    unsigned r = v.u + 0x7fffu + ((v.u >> 16) & 1u);   // RNE
    return (ushort)(r >> 16);
}

#if __has_builtin(__builtin_amdgcn_cvt_pk_bf16_f32)
typedef __attribute__((ext_vector_type(2))) __bf16 bf16x2v;
__device__ __forceinline__ unsigned pack_bf2(float a, float b) {
    union { bf16x2v v; unsigned u; } cv;
    cv.v = __builtin_amdgcn_cvt_pk_bf16_f32(a, b);
    return cv.u;
}
#else
__device__ __forceinline__ unsigned pack_bf2(float a, float b) {
    union { __hip_bfloat162 h2; unsigned u; } cv;
    cv.h2 = __float22bfloat162_rn(make_float2(a, b));
    return cv.u;
}
#endif

// async global->LDS, 16B per lane; lds base wave-uniform, lane i -> base+i*16B.
__device__ __forceinline__ void gl_lds16(const ushort* g, ushort* l) {
    __builtin_amdgcn_global_load_lds(
        (const __attribute__((address_space(1))) unsigned*)g,
        (__attribute__((address_space(3))) unsigned*)l, 16, 0, 0);
}

// ---------- convert x (fp32 -> bf16), 8 elems/thread ----------
__global__ __launch_bounds__(256) void cvt_x(const float* __restrict__ x,
                                             ushort* __restrict__ xb) {
    int i = blockIdx.x * 256 + threadIdx.x;
    const float4* p = (const float4*)x + 2 * (size_t)i;
    float4 a = p[0], bq = p[1];
    union { ushort s[8]; uint4 v; } u;
    u.s[0] = f2bf(a.x);  u.s[1] = f2bf(a.y);  u.s[2] = f2bf(a.z);  u.s[3] = f2bf(a.w);
    u.s[4] = f2bf(bq.x); u.s[5] = f2bf(bq.y); u.s[6] = f2bf(bq.z); u.s[7] = f2bf(bq.w);
    *(uint4*)&xb[(size_t)i * 8] = u.v;
}

// ---------- transpose + convert: W[K][N] fp32 -> Wt[N][K] bf16 ----------
__global__ __launch_bounds__(256) void tr_cvt(const float* __restrict__ W,
                                              ushort* __restrict__ Wt, int K, int N) {
    __shared__ float T[32][33];
    int t = threadIdx.x;
    int k0 = blockIdx.y * 32, n0 = blockIdx.x * 32;
    int r = t >> 3, c4 = (t & 7) * 4;
    float4 v = *(const float4*)&W[(size_t)(k0 + r) * N + n0 + c4];
    T[r][c4] = v.x; T[r][c4 + 1] = v.y; T[r][c4 + 2] = v.z; T[r][c4 + 3] = v.w;
    __syncthreads();
    union { ushort s[4]; unsigned long long u; } o;
    o.s[0] = f2bf(T[c4 + 0][r]);
    o.s[1] = f2bf(T[c4 + 1][r]);
    o.s[2] = f2bf(T[c4 + 2][r]);
    o.s[3] = f2bf(T[c4 + 3][r]);
    *(unsigned long long*)&Wt[(size_t)(n0 + r) * K + k0 + c4] = o.u;
}

// ---------- V^T per head: qkvb v-block [tok][d] -> Vt[bh][d][N_] ----------
__global__ __launch_bounds__(256) void vtrans(const ushort* __restrict__ qkvb,
                                              ushort* __restrict__ Vt) {
    __shared__ ushort T[64 * 64];
    const int tid = threadIdx.x;
    const int t0 = blockIdx.x * 64, bh = blockIdx.y;
    const int b = bh / H_, h = bh % H_;
#pragma unroll
    for (int i = 0; i < 2; i++) {
        int c = i * 256 + tid;          // 0..511
        int tok = c >> 3, dc = c & 7;   // token, d-chunk
        uint4 v = *(const uint4*)&qkvb[((size_t)b * N_ + t0 + tok) * (3 * C_)
                                       + 2 * C_ + h * D_ + dc * 8];
        const ushort* vs = (const ushort*)&v;
#pragma unroll
        for (int j = 0; j < 8; j++) {
            int d = dc * 8 + j;
            int sc = (tok >> 3) ^ (d & 7) ^ (d >> 3);
            T[d * 64 + sc * 8 + (tok & 7)] = vs[j];
        }
    }
    __syncthreads();
#pragma unroll
    for (int i = 0; i < 2; i++) {
        int c = i * 256 + tid;
        int d = c >> 3, tc = c & 7;
        int sc = tc ^ (d & 7) ^ (d >> 3);
        uint4 o = *(const uint4*)&T[d * 64 + sc * 8];
        *(uint4*)&Vt[((size_t)bh * D_ + d) * N_ + t0 + tc * 8] = o;
    }
}

// ---------- bf16 MFMA GEMM: A[M][K] bf16, Bt[N][K] bf16, +bias ----------
// 128x128 tile, BK=32, 4 waves each 64x64, global_load_lds + XOR swizzle.
// OBF (qkv path): bf16 output, q-zone cols scaled by SC_LOG2E.
template <bool OBF>
__global__ __launch_bounds__(256) void gemm_bf16(
    const ushort* __restrict__ A, const ushort* __restrict__ Bt,
    const float* __restrict__ bias, void* __restrict__ outp,
    int M, int N, int K)
{
    __shared__ ushort Asl[128 * 32];
    __shared__ ushort Bsl[128 * 32];

    const int tid  = threadIdx.x;
    const int lane = tid & 63, w = tid >> 6;
    const int quad = lane >> 4, l16 = lane & 15;
    const int row0 = blockIdx.y * 128, col0 = blockIdx.x * 128;
    const int mh = (w >> 1) * 64, nh = (w & 1) * 64;
    const int sw = (quad ^ (l16 & 3)) * 8;

    f32x4 acc[4][4];
#pragma unroll
    for (int i = 0; i < 4; i++)
#pragma unroll
        for (int j = 0; j < 4; j++) acc[i][j] = (f32x4)0.f;

    for (int k0 = 0; k0 < K; k0 += 32) {
#pragma unroll
        for (int i = 0; i < 2; i++) {
            int c  = i * 256 + w * 64 + lane;
            int rr = c >> 2;
            int cc = (c & 3) ^ (rr & 3);
            int wb = (i * 256 + w * 64) * 8;
            gl_lds16(&A[(size_t)(row0 + rr) * K + k0 + cc * 8], &Asl[wb]);
            gl_lds16(&Bt[(size_t)(col0 + rr) * K + k0 + cc * 8], &Bsl[wb]);
        }
        __syncthreads();
        bf16x8 af[4], bfr[4];
#pragma unroll
        for (int mt = 0; mt < 4; mt++)
            af[mt] = *(const bf16x8*)&Asl[(mh + mt * 16 + l16) * 32 + sw];
#pragma unroll
        for (int nt = 0; nt < 4; nt++)
            bfr[nt] = *(const bf16x8*)&Bsl[(nh + nt * 16 + l16) * 32 + sw];
#pragma unroll
        for (int mt = 0; mt < 4; mt++)
#pragma unroll
            for (int nt = 0; nt < 4; nt++)
                acc[mt][nt] = MFMA16(af[mt], bfr[nt], acc[mt][nt]);
        __syncthreads();
    }

    const float scl = (OBF && col0 < C_) ? SC_LOG2E : 1.f;
#pragma unroll
    for (int nt = 0; nt < 4; nt++) {
        int col = col0 + nh + nt * 16 + l16;
        float bv = bias[col];
#pragma unroll
        for (int mt = 0; mt < 4; mt++) {
            f32x4 v = acc[mt][nt];
#pragma unroll
            for (int r = 0; r < 4; r++) {
                int row = row0 + mh + mt * 16 + quad * 4 + r;
                if (OBF)
                    ((ushort*)outp)[(size_t)row * N + col] = f2bf((v[r] + bv) * scl);
                else
                    ((float*)outp)[(size_t)row * N + col] = v[r] + bv;
            }
        }
    }
}

// ---------- MFMA flash attention ----------
// Fixed-max softmax (Q pre-scaled by 0.125*log2e -> p = exp2(s)).
// Key insight: S^T C-layout (key = 16kt + 4quad + r) EQUALS the B-operand
// layout of mfma_f32_16x16x16_bf16 (k = 4quad + j) per 16-key chunk, so the
// packed exp(sacc) registers feed the PV MFMA directly -- no P transform.
__global__ __launch_bounds__(256) void attn_mfma(
    const ushort* __restrict__ qkvb, const ushort* __restrict__ Vt,
    ushort* __restrict__ attnb)
{
    __shared__ ushort Kd[2][64 * 64];     // [key][d], swizzled 16B chunks
    __shared__ ushort Vd[2][64 * 64];     // [d][key], swizzled 16B chunks

    const int tid  = threadIdx.x;
    const int lane = tid & 63, w = tid >> 6;
    const int quad = lane >> 4, l16 = lane & 15;
    const int bh = blockIdx.y, b = bh / H_, h = bh % H_;
    const int q0 = blockIdx.x * 128 + w * 32;
    const size_t rowbase = (size_t)b * N_;
    const int hoff = h * D_;
    const f32x4 Z4 = {0.f, 0.f, 0.f, 0.f};

    const ushort* Kg = qkvb + rowbase * (3 * C_) + C_ + hoff;  // + tok*(3C)
    const ushort* Vg = Vt + (size_t)bh * D_ * N_;              // + d*N_ + tok

    // per-lane staging coords (two 16B chunks per buffer per thread)
    int rr0, cc0, rr1, cc1, wb0, wb1;
    {
        int c0 = w * 64 + lane, c1 = 256 + w * 64 + lane;
        rr0 = c0 >> 3; cc0 = (c0 & 7) ^ (rr0 & 7); wb0 = (w * 64) * 8;
        rr1 = c1 >> 3; cc1 = (c1 & 7) ^ (rr1 & 7); wb1 = (256 + w * 64) * 8;
    }
    const ushort* kp0 = Kg + (size_t)rr0 * (3 * C_) + cc0 * 8;
    const ushort* kp1 = Kg + (size_t)rr1 * (3 * C_) + cc1 * 8;
    const ushort* vp0 = Vg + (size_t)rr0 * N_ + cc0 * 8;
    const ushort* vp1 = Vg + (size_t)rr1 * N_ + cc1 * 8;

    // Q fragments in registers (pre-scaled in qkvb)
    bf16x8 Qf[2][2];
#pragma unroll
    for (int qt = 0; qt < 2; qt++)
#pragma unroll
        for (int c = 0; c < 2; c++)
            Qf[qt][c] = *(const bf16x8*)&qkvb[(rowbase + q0 + qt * 16 + l16) * (3 * C_)
                                              + hoff + c * 32 + quad * 8];

    f32x4 oacc[4][2];
#pragma unroll
    for (int dt = 0; dt < 4; dt++)
#pragma unroll
        for (int qt = 0; qt < 2; qt++) oacc[dt][qt] = (f32x4)0.f;
    float lrow[2] = {0.f, 0.f};

    // stage tile 0 into buffer 0; advance pointers to tile 1
    gl_lds16(kp0, &Kd[0][wb0]);
    gl_lds16(vp0, &Vd[0][wb0]);
    gl_lds16(kp1, &Kd[0][wb1]);
    gl_lds16(vp1, &Vd[0][wb1]);
    kp0 += 64 * 3 * C_; kp1 += 64 * 3 * C_; vp0 += 64; vp1 += 64;
    __syncthreads();

#define TILE_BODY(CB, PREFETCH)                                               \
    {                                                                         \
        if (PREFETCH) {                                                       \
            gl_lds16(kp0, &Kd[(CB) ^ 1][wb0]);                                \
            gl_lds16(vp0, &Vd[(CB) ^ 1][wb0]);                                \
            gl_lds16(kp1, &Kd[(CB) ^ 1][wb1]);                                \
            gl_lds16(vp1, &Vd[(CB) ^ 1][wb1]);                                \
        }                                                                     \
        kp0 += 64 * 3 * C_; kp1 += 64 * 3 * C_; vp0 += 64; vp1 += 64;         \
        f32x4 sacc[4][2];                                                     \
        {   /* S^T c=0: MFMA with zero C operand */                           \
            bf16x8 kf[4];                                                     \
            _Pragma("unroll")                                                 \
            for (int kt = 0; kt < 4; kt++)                                    \
                kf[kt] = *(const bf16x8*)&Kd[CB][(kt * 16 + l16) * 64         \
                                               + ((quad) ^ (l16 & 7)) * 8];   \
            _Pragma("unroll")                                                 \
            for (int kt = 0; kt < 4; kt++)                                    \
                _Pragma("unroll")                                             \
                for (int qt = 0; qt < 2; qt++)                                \
                    sacc[kt][qt] = MFMA16(kf[kt], Qf[qt][0], Z4);             \
        }                                                                     \
        {   /* S^T c=1: accumulate */                                         \
            bf16x8 kf[4];                                                     \
            _Pragma("unroll")                                                 \
            for (int kt = 0; kt < 4; kt++)                                    \
                kf[kt] = *(const bf16x8*)&Kd[CB][(kt * 16 + l16) * 64         \
                                               + ((4 | quad) ^ (l16 & 7)) * 8]; \
            _Pragma("unroll")                                                 \
            for (int kt = 0; kt < 4; kt++)                                    \
                _Pragma("unroll")                                             \
                for (int qt = 0; qt < 2; qt++)                                \
                    sacc[kt][qt] = MFMA16(kf[kt], Qf[qt][1], sacc[kt][qt]);   \
        }                                                                     \
        union { unsigned u[2]; bf16x4 v; } pf[2][4];                          \
        _Pragma("unroll")                                                     \
        for (int qt = 0; qt < 2; qt++) {                                      \
            float sum = 0.f;                                                  \
            _Pragma("unroll")                                                 \
            for (int kt = 0; kt < 4; kt++) {                                  \
                float p0 = EXP2F(sacc[kt][qt][0]);                            \
                float p1 = EXP2F(sacc[kt][qt][1]);                            \
                float p2 = EXP2F(sacc[kt][qt][2]);                            \
                float p3 = EXP2F(sacc[kt][qt][3]);                            \
                sum += (p0 + p1) + (p2 + p3);                                 \
                pf[qt][kt].u[0] = pack_bf2(p0, p1);                           \
                pf[qt][kt].u[1] = pack_bf2(p2, p3);                           \
            }                                                                 \
            lrow[qt] += sum;                                                  \
        }                                                                     \
        _Pragma("unroll")                                                     \
        for (int c16 = 0; c16 < 4; c16++) {                                   \
            /* V^T A-frag: A[m=d][k=16c16+4quad+j], 4 bf16 = ds_read_b64 */   \
            const int vcol = ((2 * c16 + (quad >> 1)) ^ (l16 & 7)) * 8        \
                             + (quad & 1) * 4;                                \
            _Pragma("unroll")                                                 \
            for (int dt = 0; dt < 4; dt++) {                                  \
                bf16x4 vf = *(const bf16x4*)&Vd[CB][(dt * 16 + l16) * 64 + vcol]; \
                _Pragma("unroll")                                             \
                for (int qt = 0; qt < 2; qt++)                                \
                    oacc[dt][qt] = MFMAK16(vf, pf[qt][c16].v, oacc[dt][qt]);  \
            }                                                                 \
        }                                                                     \
        __syncthreads();                                                      \
    }

    for (int tt = 0; tt < 16; tt++) {
        TILE_BODY(0, 1)
        TILE_BODY(1, (tt < 15))
    }
#undef TILE_BODY

    // epilogue: cross-quad l reduce, normalize, write bf16 [B*N][C]
#pragma unroll
    for (int qt = 0; qt < 2; qt++) {
        float s = lrow[qt];
        s += __shfl_xor(s, 16, 64);
        s += __shfl_xor(s, 32, 64);
        float inv = 1.f / s;
        size_t orow = (rowbase + q0 + qt * 16 + l16) * C_ + hoff;
#pragma unroll
        for (int dt = 0; dt < 4; dt++) {
            union { ushort us[4]; unsigned long long u; } o;
#pragma unroll
            for (int r = 0; r < 4; r++) o.us[r] = f2bf(oacc[dt][qt][r] * inv);
            *(unsigned long long*)&attnb[orow + dt * 16 + quad * 4] = o.u;
        }
    }
}

// ---------------- launcher ----------------
extern "C" void kernel_launch(void* const* d_in, const int* in_sizes, int n_in,
                              void* d_out, int out_size, void* d_ws, size_t ws_size,
                              hipStream_t stream)
{
    const float* x     = (const float*)d_in[0];
    const float* Wqkv  = (const float*)d_in[1];
    const float* bqkv  = (const float*)d_in[2];
    const float* Wproj = (const float*)d_in[3];
    const float* bproj = (const float*)d_in[4];

    ushort* xb     = (ushort*)d_ws;                                    // [8192][768]
    ushort* Wqkvt  = xb + (size_t)B_ * N_ * C_;                        // [2304][768]
    ushort* Wprojt = Wqkvt + (size_t)3 * C_ * C_;                      // [768][768]
    ushort* qkvb   = Wprojt + (size_t)C_ * C_;                         // [8192][2304]
    ushort* attnb  = qkvb + (size_t)B_ * N_ * 3 * C_;                  // [8192][768]
    ushort* Vtb    = attnb + (size_t)B_ * N_ * C_;                     // [48][64][2048]

    const int M = B_ * N_;

    cvt_x<<<(M * C_) / (8 * 256), 256, 0, stream>>>(x, xb);
    tr_cvt<<<dim3((3 * C_) / 32, C_ / 32), 256, 0, stream>>>(Wqkv, Wqkvt, C_, 3 * C_);
    tr_cvt<<<dim3(C_ / 32, C_ / 32), 256, 0, stream>>>(Wproj, Wprojt, C_, C_);

    gemm_bf16<true><<<dim3((3 * C_) / 128, M / 128), 256, 0, stream>>>(
        xb, Wqkvt, bqkv, qkvb, M, 3 * C_, C_);

    vtrans<<<dim3(N_ / 64, B_ * H_), 256, 0, stream>>>(qkvb, Vtb);

    attn_mfma<<<dim3(N_ / 128, B_ * H_), 256, 0, stream>>>(qkvb, Vtb, attnb);

    gemm_bf16<false><<<dim3(C_ / 128, M / 128), 256, 0, stream>>>(
        attnb, Wprojt, bproj, d_out, M, C_, C_);
}

// Round 9
// 248.916 us; speedup vs baseline: 1.0533x; 1.0149x over previous
//
#include <hip/hip_runtime.h>
#include <hip/hip_bf16.h>
#include <math.h>

#define B_ 4
#define N_ 2048
#define C_ 768
#define H_ 12
#define D_ 64
#define SC_LOG2E 0.18033688f   // 0.125 * log2(e), folded into stored Q

typedef __attribute__((ext_vector_type(8))) short bf16x8;
typedef __attribute__((ext_vector_type(4))) float f32x4;

#define MFMA16(A, B, C) __builtin_amdgcn_mfma_f32_16x16x32_bf16(A, B, C, 0, 0, 0)

#if __has_builtin(__builtin_amdgcn_exp2f)
#define EXP2F(x) __builtin_amdgcn_exp2f(x)
#else
#define EXP2F(x) exp2f(x)
#endif

__device__ __forceinline__ ushort f2bf(float f) {
    union { float f; unsigned u; } v; v.f = f;
    unsigned r = v.u + 0x7fffu + ((v.u >> 16) & 1u);   // RNE
    return (ushort)(r >> 16);
}

#if __has_builtin(__builtin_amdgcn_cvt_pk_bf16_f32)
typedef __attribute__((ext_vector_type(2))) __bf16 bf16x2v;
__device__ __forceinline__ unsigned pack_bf2(float a, float b) {
    union { bf16x2v v; unsigned u; } cv;
    cv.v = __builtin_amdgcn_cvt_pk_bf16_f32(a, b);
    return cv.u;
}
#else
__device__ __forceinline__ unsigned pack_bf2(float a, float b) {
    union { __hip_bfloat162 h2; unsigned u; } cv;
    cv.h2 = __float22bfloat162_rn(make_float2(a, b));
    return cv.u;
}
#endif

// async global->LDS, 16B per lane; lds base wave-uniform, lane i -> base+i*16B.
__device__ __forceinline__ void gl_lds16(const ushort* g, ushort* l) {
    __builtin_amdgcn_global_load_lds(
        (const __attribute__((address_space(1))) unsigned*)g,
        (__attribute__((address_space(3))) unsigned*)l, 16, 0, 0);
}

// ---------- fused prep: x cvt + Wqkv transpose + Wproj transpose ----------
// grid sections: [0,3072) cvt_x, [3072,4800) Wqkv tr, [4800,5376) Wproj tr.
__device__ __forceinline__ void tr_body(const float* __restrict__ W,
                                        ushort* __restrict__ Wt,
                                        int K, int N, int bx, int by, int t) {
    __shared__ float T[32][33];
    int k0 = by * 32, n0 = bx * 32;
    int r = t >> 3, c4 = (t & 7) * 4;
    float4 v = *(const float4*)&W[(size_t)(k0 + r) * N + n0 + c4];
    T[r][c4] = v.x; T[r][c4 + 1] = v.y; T[r][c4 + 2] = v.z; T[r][c4 + 3] = v.w;
    __syncthreads();
    union { ushort s[4]; unsigned long long u; } o;
    o.s[0] = f2bf(T[c4 + 0][r]);
    o.s[1] = f2bf(T[c4 + 1][r]);
    o.s[2] = f2bf(T[c4 + 2][r]);
    o.s[3] = f2bf(T[c4 + 3][r]);
    *(unsigned long long*)&Wt[(size_t)(n0 + r) * K + k0 + c4] = o.u;
}

__global__ __launch_bounds__(256) void prep(
    const float* __restrict__ x, ushort* __restrict__ xb,
    const float* __restrict__ Wqkv, ushort* __restrict__ Wqkvt,
    const float* __restrict__ Wproj, ushort* __restrict__ Wprojt)
{
    const int bid = blockIdx.x, t = threadIdx.x;
    if (bid < 3072) {
        int i = bid * 256 + t;
        const float4* p = (const float4*)x + 2 * (size_t)i;
        float4 a = p[0], bq = p[1];
        union { ushort s[8]; uint4 v; } u;
        u.s[0] = f2bf(a.x);  u.s[1] = f2bf(a.y);  u.s[2] = f2bf(a.z);  u.s[3] = f2bf(a.w);
        u.s[4] = f2bf(bq.x); u.s[5] = f2bf(bq.y); u.s[6] = f2bf(bq.z); u.s[7] = f2bf(bq.w);
        *(uint4*)&xb[(size_t)i * 8] = u.v;
    } else if (bid < 4800) {
        int id = bid - 3072;                    // 72 x 24
        tr_body(Wqkv, Wqkvt, C_, 3 * C_, id % 72, id / 72, t);
    } else {
        int id = bid - 4800;                    // 24 x 24
        tr_body(Wproj, Wprojt, C_, C_, id % 24, id / 24, t);
    }
}

// ---------- V^T per head: qkvb v-block [tok][d] -> Vt[bh][d][N_] ----------
__global__ __launch_bounds__(256) void vtrans(const ushort* __restrict__ qkvb,
                                              ushort* __restrict__ Vt) {
    __shared__ ushort T[64 * 64];
    const int tid = threadIdx.x;
    const int t0 = blockIdx.x * 64, bh = blockIdx.y;
    const int b = bh / H_, h = bh % H_;
#pragma unroll
    for (int i = 0; i < 2; i++) {
        int c = i * 256 + tid;          // 0..511
        int tok = c >> 3, dc = c & 7;   // token, d-chunk
        uint4 v = *(const uint4*)&qkvb[((size_t)b * N_ + t0 + tok) * (3 * C_)
                                       + 2 * C_ + h * D_ + dc * 8];
        const ushort* vs = (const ushort*)&v;
#pragma unroll
        for (int j = 0; j < 8; j++) {
            int d = dc * 8 + j;
            int sc = (tok >> 3) ^ (d & 7) ^ (d >> 3);
            T[d * 64 + sc * 8 + (tok & 7)] = vs[j];
        }
    }
    __syncthreads();
#pragma unroll
    for (int i = 0; i < 2; i++) {
        int c = i * 256 + tid;
        int d = c >> 3, tc = c & 7;
        int sc = tc ^ (d & 7) ^ (d >> 3);
        uint4 o = *(const uint4*)&T[d * 64 + sc * 8];
        *(uint4*)&Vt[((size_t)bh * D_ + d) * N_ + t0 + tc * 8] = o;
    }
}

// ---------- bf16 MFMA GEMM: A[M][K] bf16, Bt[N][K] bf16, +bias ----------
// 128x128 tile, BK=32, 4 waves each 64x64, global_load_lds + XOR swizzle.
// OBF (qkv path): bf16 output, q-zone cols scaled by SC_LOG2E.
template <bool OBF>
__global__ __launch_bounds__(256) void gemm_bf16(
    const ushort* __restrict__ A, const ushort* __restrict__ Bt,
    const float* __restrict__ bias, void* __restrict__ outp,
    int M, int N, int K)
{
    __shared__ ushort Asl[128 * 32];
    __shared__ ushort Bsl[128 * 32];

    const int tid  = threadIdx.x;
    const int lane = tid & 63, w = tid >> 6;
    const int quad = lane >> 4, l16 = lane & 15;
    const int row0 = blockIdx.y * 128, col0 = blockIdx.x * 128;
    const int mh = (w >> 1) * 64, nh = (w & 1) * 64;
    const int sw = (quad ^ (l16 & 3)) * 8;

    f32x4 acc[4][4];
#pragma unroll
    for (int i = 0; i < 4; i++)
#pragma unroll
        for (int j = 0; j < 4; j++) acc[i][j] = (f32x4)0.f;

    for (int k0 = 0; k0 < K; k0 += 32) {
#pragma unroll
        for (int i = 0; i < 2; i++) {
            int c  = i * 256 + w * 64 + lane;
            int rr = c >> 2;
            int cc = (c & 3) ^ (rr & 3);
            int wb = (i * 256 + w * 64) * 8;
            gl_lds16(&A[(size_t)(row0 + rr) * K + k0 + cc * 8], &Asl[wb]);
            gl_lds16(&Bt[(size_t)(col0 + rr) * K + k0 + cc * 8], &Bsl[wb]);
        }
        __syncthreads();
        bf16x8 af[4], bfr[4];
#pragma unroll
        for (int mt = 0; mt < 4; mt++)
            af[mt] = *(const bf16x8*)&Asl[(mh + mt * 16 + l16) * 32 + sw];
#pragma unroll
        for (int nt = 0; nt < 4; nt++)
            bfr[nt] = *(const bf16x8*)&Bsl[(nh + nt * 16 + l16) * 32 + sw];
#pragma unroll
        for (int mt = 0; mt < 4; mt++)
#pragma unroll
            for (int nt = 0; nt < 4; nt++)
                acc[mt][nt] = MFMA16(af[mt], bfr[nt], acc[mt][nt]);
        __syncthreads();
    }

    const float scl = (OBF && col0 < C_) ? SC_LOG2E : 1.f;
#pragma unroll
    for (int nt = 0; nt < 4; nt++) {
        int col = col0 + nh + nt * 16 + l16;
        float bv = bias[col];
#pragma unroll
        for (int mt = 0; mt < 4; mt++) {
            f32x4 v = acc[mt][nt];
#pragma unroll
            for (int r = 0; r < 4; r++) {
                int row = row0 + mh + mt * 16 + quad * 4 + r;
                if (OBF)
                    ((ushort*)outp)[(size_t)row * N + col] = f2bf((v[r] + bv) * scl);
                else
                    ((float*)outp)[(size_t)row * N + col] = v[r] + bv;
            }
        }
    }
}

// ---------- MFMA flash attention (round-6 measured-best body) ----------
// Fixed-max softmax (Q pre-scaled by 0.125*log2e -> p = exp2(s)). P^T via
// per-wave LDS round-trip; K/V^T staged via global_load_lds double buffers
// with prefetch-before-compute; tile loop unrolled x2 (compile-time parity).
__global__ __launch_bounds__(256) void attn_mfma(
    const ushort* __restrict__ qkvb, const ushort* __restrict__ Vt,
    ushort* __restrict__ attnb)
{
    __shared__ ushort Kd[2][64 * 64];     // [key][d], swizzled 16B chunks
    __shared__ ushort Vd[2][64 * 64];     // [d][key], swizzled 16B chunks
    __shared__ ushort Ptl[4 * 32 * 72];   // per-wave P^T [q][key], pad 72

    const int tid  = threadIdx.x;
    const int lane = tid & 63, w = tid >> 6;
    const int quad = lane >> 4, l16 = lane & 15;
    const int bh = blockIdx.y, b = bh / H_, h = bh % H_;
    const int q0 = blockIdx.x * 128 + w * 32;
    const size_t rowbase = (size_t)b * N_;
    const int hoff = h * D_;
    ushort* Ptw = Ptl + w * 32 * 72;
    const f32x4 Z4 = {0.f, 0.f, 0.f, 0.f};

    const ushort* Kg = qkvb + rowbase * (3 * C_) + C_ + hoff;  // + tok*(3C)
    const ushort* Vg = Vt + (size_t)bh * D_ * N_;              // + d*N_ + tok

    // per-lane staging coords (two 16B chunks per buffer per thread)
    int rr0, cc0, rr1, cc1, wb0, wb1;
    {
        int c0 = w * 64 + lane, c1 = 256 + w * 64 + lane;
        rr0 = c0 >> 3; cc0 = (c0 & 7) ^ (rr0 & 7); wb0 = (w * 64) * 8;
        rr1 = c1 >> 3; cc1 = (c1 & 7) ^ (rr1 & 7); wb1 = (256 + w * 64) * 8;
    }
    const ushort* kp0 = Kg + (size_t)rr0 * (3 * C_) + cc0 * 8;
    const ushort* kp1 = Kg + (size_t)rr1 * (3 * C_) + cc1 * 8;
    const ushort* vp0 = Vg + (size_t)rr0 * N_ + cc0 * 8;
    const ushort* vp1 = Vg + (size_t)rr1 * N_ + cc1 * 8;

    // Q fragments in registers (pre-scaled in qkvb)
    bf16x8 Qf[2][2];
#pragma unroll
    for (int qt = 0; qt < 2; qt++)
#pragma unroll
        for (int c = 0; c < 2; c++)
            Qf[qt][c] = *(const bf16x8*)&qkvb[(rowbase + q0 + qt * 16 + l16) * (3 * C_)
                                              + hoff + c * 32 + quad * 8];

    f32x4 oacc[4][2];
#pragma unroll
    for (int dt = 0; dt < 4; dt++)
#pragma unroll
        for (int qt = 0; qt < 2; qt++) oacc[dt][qt] = (f32x4)0.f;
    float lrow[2] = {0.f, 0.f};

    // stage tile 0 into buffer 0; advance pointers to tile 1
    gl_lds16(kp0, &Kd[0][wb0]);
    gl_lds16(vp0, &Vd[0][wb0]);
    gl_lds16(kp1, &Kd[0][wb1]);
    gl_lds16(vp1, &Vd[0][wb1]);
    kp0 += 64 * 3 * C_; kp1 += 64 * 3 * C_; vp0 += 64; vp1 += 64;
    __syncthreads();

#define TILE_BODY(CB, PREFETCH)                                               \
    {                                                                         \
        if (PREFETCH) {                                                       \
            gl_lds16(kp0, &Kd[(CB) ^ 1][wb0]);                                \
            gl_lds16(vp0, &Vd[(CB) ^ 1][wb0]);                                \
            gl_lds16(kp1, &Kd[(CB) ^ 1][wb1]);                                \
            gl_lds16(vp1, &Vd[(CB) ^ 1][wb1]);                                \
        }                                                                     \
        kp0 += 64 * 3 * C_; kp1 += 64 * 3 * C_; vp0 += 64; vp1 += 64;         \
        f32x4 sacc[4][2];                                                     \
        {   /* c = 0: MFMA with zero C operand */                             \
            bf16x8 kf[4];                                                     \
            _Pragma("unroll")                                                 \
            for (int kt = 0; kt < 4; kt++)                                    \
                kf[kt] = *(const bf16x8*)&Kd[CB][(kt * 16 + l16) * 64         \
                                               + ((quad) ^ (l16 & 7)) * 8];   \
            _Pragma("unroll")                                                 \
            for (int kt = 0; kt < 4; kt++)                                    \
                _Pragma("unroll")                                             \
                for (int qt = 0; qt < 2; qt++)                                \
                    sacc[kt][qt] = MFMA16(kf[kt], Qf[qt][0], Z4);             \
        }                                                                     \
        {   /* c = 1: accumulate */                                           \
            bf16x8 kf[4];                                                     \
            _Pragma("unroll")                                                 \
            for (int kt = 0; kt < 4; kt++)                                    \
                kf[kt] = *(const bf16x8*)&Kd[CB][(kt * 16 + l16) * 64         \
                                               + ((4 | quad) ^ (l16 & 7)) * 8]; \
            _Pragma("unroll")                                                 \
            for (int kt = 0; kt < 4; kt++)                                    \
                _Pragma("unroll")                                             \
                for (int qt = 0; qt < 2; qt++)                                \
                    sacc[kt][qt] = MFMA16(kf[kt], Qf[qt][1], sacc[kt][qt]);   \
        }                                                                     \
        _Pragma("unroll")                                                     \
        for (int qt = 0; qt < 2; qt++) {                                      \
            float sum = 0.f;                                                  \
            _Pragma("unroll")                                                 \
            for (int kt = 0; kt < 4; kt++) {                                  \
                float p0 = EXP2F(sacc[kt][qt][0]);                            \
                float p1 = EXP2F(sacc[kt][qt][1]);                            \
                float p2 = EXP2F(sacc[kt][qt][2]);                            \
                float p3 = EXP2F(sacc[kt][qt][3]);                            \
                sum += (p0 + p1) + (p2 + p3);                                 \
                uint2 pk;                                                     \
                pk.x = pack_bf2(p0, p1);                                      \
                pk.y = pack_bf2(p2, p3);                                      \
                *(uint2*)&Ptw[(qt * 16 + l16) * 72 + kt * 16 + quad * 4] = pk; \
            }                                                                 \
            lrow[qt] += sum;                                                  \
        }                                                                     \
        _Pragma("unroll")                                                     \
        for (int c = 0; c < 2; c++) {                                         \
            bf16x8 pf[2];                                                     \
            _Pragma("unroll")                                                 \
            for (int qt = 0; qt < 2; qt++)                                    \
                pf[qt] = *(const bf16x8*)&Ptw[(qt * 16 + l16) * 72            \
                                              + c * 32 + quad * 8];           \
            _Pragma("unroll")                                                 \
            for (int dt = 0; dt < 4; dt++) {                                  \
                bf16x8 vf = *(const bf16x8*)&Vd[CB][(dt * 16 + l16) * 64      \
                                   + (((c << 2) | quad) ^ (l16 & 7)) * 8];    \
                _Pragma("unroll")                                             \
                for (int qt = 0; qt < 2; qt++)                                \
                    oacc[dt][qt] = MFMA16(vf, pf[qt], oacc[dt][qt]);          \
            }                                                                 \
        }                                                                     \
        __syncthreads();                                                      \
    }

    for (int tt = 0; tt < 16; tt++) {
        TILE_BODY(0, 1)
        TILE_BODY(1, (tt < 15))
    }
#undef TILE_BODY

    // epilogue: cross-quad l reduce, normalize, write bf16 [B*N][C]
#pragma unroll
    for (int qt = 0; qt < 2; qt++) {
        float s = lrow[qt];
        s += __shfl_xor(s, 16, 64);
        s += __shfl_xor(s, 32, 64);
        float inv = 1.f / s;
        size_t orow = (rowbase + q0 + qt * 16 + l16) * C_ + hoff;
#pragma unroll
        for (int dt = 0; dt < 4; dt++) {
            union { ushort us[4]; unsigned long long u; } o;
#pragma unroll
            for (int r = 0; r < 4; r++) o.us[r] = f2bf(oacc[dt][qt][r] * inv);
            *(unsigned long long*)&attnb[orow + dt * 16 + quad * 4] = o.u;
        }
    }
}

// ---------------- launcher ----------------
extern "C" void kernel_launch(void* const* d_in, const int* in_sizes, int n_in,
                              void* d_out, int out_size, void* d_ws, size_t ws_size,
                              hipStream_t stream)
{
    const float* x     = (const float*)d_in[0];
    const float* Wqkv  = (const float*)d_in[1];
    const float* bqkv  = (const float*)d_in[2];
    const float* Wproj = (const float*)d_in[3];
    const float* bproj = (const float*)d_in[4];

    ushort* xb     = (ushort*)d_ws;                                    // [8192][768]
    ushort* Wqkvt  = xb + (size_t)B_ * N_ * C_;                        // [2304][768]
    ushort* Wprojt = Wqkvt + (size_t)3 * C_ * C_;                      // [768][768]
    ushort* qkvb   = Wprojt + (size_t)C_ * C_;                         // [8192][2304]
    ushort* attnb  = qkvb + (size_t)B_ * N_ * 3 * C_;                  // [8192][768]
    ushort* Vtb    = attnb + (size_t)B_ * N_ * C_;                     // [48][64][2048]

    const int M = B_ * N_;

    prep<<<5376, 256, 0, stream>>>(x, xb, Wqkv, Wqkvt, Wproj, Wprojt);

    gemm_bf16<true><<<dim3((3 * C_) / 128, M / 128), 256, 0, stream>>>(
        xb, Wqkvt, bqkv, qkvb, M, 3 * C_, C_);

    vtrans<<<dim3(N_ / 64, B_ * H_), 256, 0, stream>>>(qkvb, Vtb);

    attn_mfma<<<dim3(N_ / 128, B_ * H_), 256, 0, stream>>>(qkvb, Vtb, attnb);

    gemm_bf16<false><<<dim3(C_ / 128, M / 128), 256, 0, stream>>>(
        attnb, Wprojt, bproj, d_out, M, C_, C_);
}

// Round 10
// 246.982 us; speedup vs baseline: 1.0616x; 1.0078x over previous
//
#include <hip/hip_runtime.h>
#include <hip/hip_bf16.h>
#include <math.h>

#define B_ 4
#define N_ 2048
#define C_ 768
#define H_ 12
#define D_ 64
#define SC_LOG2E 0.18033688f   // 0.125 * log2(e), folded into stored Q

typedef __attribute__((ext_vector_type(8))) short bf16x8;
typedef __attribute__((ext_vector_type(4))) float f32x4;

#define MFMA16(A, B, C) __builtin_amdgcn_mfma_f32_16x16x32_bf16(A, B, C, 0, 0, 0)

#if __has_builtin(__builtin_amdgcn_exp2f)
#define EXP2F(x) __builtin_amdgcn_exp2f(x)
#else
#define EXP2F(x) exp2f(x)
#endif

__device__ __forceinline__ ushort f2bf(float f) {
    union { float f; unsigned u; } v; v.f = f;
    unsigned r = v.u + 0x7fffu + ((v.u >> 16) & 1u);   // RNE
    return (ushort)(r >> 16);
}

#if __has_builtin(__builtin_amdgcn_cvt_pk_bf16_f32)
typedef __attribute__((ext_vector_type(2))) __bf16 bf16x2v;
__device__ __forceinline__ unsigned pack_bf2(float a, float b) {
    union { bf16x2v v; unsigned u; } cv;
    cv.v = __builtin_amdgcn_cvt_pk_bf16_f32(a, b);
    return cv.u;
}
#else
__device__ __forceinline__ unsigned pack_bf2(float a, float b) {
    union { __hip_bfloat162 h2; unsigned u; } cv;
    cv.h2 = __float22bfloat162_rn(make_float2(a, b));
    return cv.u;
}
#endif

// async global->LDS, 16B per lane; lds base wave-uniform, lane i -> base+i*16B.
__device__ __forceinline__ void gl_lds16(const ushort* g, ushort* l) {
    __builtin_amdgcn_global_load_lds(
        (const __attribute__((address_space(1))) unsigned*)g,
        (__attribute__((address_space(3))) unsigned*)l, 16, 0, 0);
}

// ---------- fused prep: x cvt + Wqkv transpose + Wproj transpose ----------
__device__ __forceinline__ void tr_body(const float* __restrict__ W,
                                        ushort* __restrict__ Wt,
                                        int K, int N, int bx, int by, int t) {
    __shared__ float T[32][33];
    int k0 = by * 32, n0 = bx * 32;
    int r = t >> 3, c4 = (t & 7) * 4;
    float4 v = *(const float4*)&W[(size_t)(k0 + r) * N + n0 + c4];
    T[r][c4] = v.x; T[r][c4 + 1] = v.y; T[r][c4 + 2] = v.z; T[r][c4 + 3] = v.w;
    __syncthreads();
    union { ushort s[4]; unsigned long long u; } o;
    o.s[0] = f2bf(T[c4 + 0][r]);
    o.s[1] = f2bf(T[c4 + 1][r]);
    o.s[2] = f2bf(T[c4 + 2][r]);
    o.s[3] = f2bf(T[c4 + 3][r]);
    *(unsigned long long*)&Wt[(size_t)(n0 + r) * K + k0 + c4] = o.u;
}

__global__ __launch_bounds__(256) void prep(
    const float* __restrict__ x, ushort* __restrict__ xb,
    const float* __restrict__ Wqkv, ushort* __restrict__ Wqkvt,
    const float* __restrict__ Wproj, ushort* __restrict__ Wprojt)
{
    const int bid = blockIdx.x, t = threadIdx.x;
    if (bid < 3072) {
        int i = bid * 256 + t;
        const float4* p = (const float4*)x + 2 * (size_t)i;
        float4 a = p[0], bq = p[1];
        union { ushort s[8]; uint4 v; } u;
        u.s[0] = f2bf(a.x);  u.s[1] = f2bf(a.y);  u.s[2] = f2bf(a.z);  u.s[3] = f2bf(a.w);
        u.s[4] = f2bf(bq.x); u.s[5] = f2bf(bq.y); u.s[6] = f2bf(bq.z); u.s[7] = f2bf(bq.w);
        *(uint4*)&xb[(size_t)i * 8] = u.v;
    } else if (bid < 4800) {
        int id = bid - 3072;                    // 72 x 24
        tr_body(Wqkv, Wqkvt, C_, 3 * C_, id % 72, id / 72, t);
    } else {
        int id = bid - 4800;                    // 24 x 24
        tr_body(Wproj, Wprojt, C_, C_, id % 24, id / 24, t);
    }
}

// ---------- V^T per head: qkvb v-block [tok][d] -> Vt[bh][d][N_] ----------
__global__ __launch_bounds__(256) void vtrans(const ushort* __restrict__ qkvb,
                                              ushort* __restrict__ Vt) {
    __shared__ ushort T[64 * 64];
    const int tid = threadIdx.x;
    const int t0 = blockIdx.x * 64, bh = blockIdx.y;
    const int b = bh / H_, h = bh % H_;
#pragma unroll
    for (int i = 0; i < 2; i++) {
        int c = i * 256 + tid;          // 0..511
        int tok = c >> 3, dc = c & 7;   // token, d-chunk
        uint4 v = *(const uint4*)&qkvb[((size_t)b * N_ + t0 + tok) * (3 * C_)
                                       + 2 * C_ + h * D_ + dc * 8];
        const ushort* vs = (const ushort*)&v;
#pragma unroll
        for (int j = 0; j < 8; j++) {
            int d = dc * 8 + j;
            int sc = (tok >> 3) ^ (d & 7) ^ (d >> 3);
            T[d * 64 + sc * 8 + (tok & 7)] = vs[j];
        }
    }
    __syncthreads();
#pragma unroll
    for (int i = 0; i < 2; i++) {
        int c = i * 256 + tid;
        int d = c >> 3, tc = c & 7;
        int sc = tc ^ (d & 7) ^ (d >> 3);
        uint4 o = *(const uint4*)&T[d * 64 + sc * 8];
        *(uint4*)&Vt[((size_t)bh * D_ + d) * N_ + t0 + tc * 8] = o;
    }
}

// ---------- bf16 MFMA GEMM: A[M][K] bf16, Bt[N][K] bf16, +bias ----------
// 128x128 tile, BK=64 single-buffered (32 KB LDS -> 4 blocks/CU), 4 waves
// each 64x64. 8-chunk rows: XOR swizzle spans all 32 banks (2-way = free).
// OBF (qkv path): bf16 output, q-zone cols scaled by SC_LOG2E.
template <bool OBF>
__global__ __launch_bounds__(256) void gemm_bf16(
    const ushort* __restrict__ A, const ushort* __restrict__ Bt,
    const float* __restrict__ bias, void* __restrict__ outp,
    int M, int N, int K)
{
    __shared__ ushort Asl[128 * 64];
    __shared__ ushort Bsl[128 * 64];

    const int tid  = threadIdx.x;
    const int lane = tid & 63, w = tid >> 6;
    const int quad = lane >> 4, l16 = lane & 15;
    const int row0 = blockIdx.y * 128, col0 = blockIdx.x * 128;
    const int mh = (w >> 1) * 64, nh = (w & 1) * 64;

    f32x4 acc[4][4];
#pragma unroll
    for (int i = 0; i < 4; i++)
#pragma unroll
        for (int j = 0; j < 4; j++) acc[i][j] = (f32x4)0.f;

    for (int k0 = 0; k0 < K; k0 += 64) {
#pragma unroll
        for (int i = 0; i < 4; i++) {
            int c  = i * 256 + w * 64 + lane;   // chunk 0..1023
            int rr = c >> 3;
            int cc = (c & 7) ^ (rr & 7);
            int wb = (i * 256 + w * 64) * 8;
            gl_lds16(&A[(size_t)(row0 + rr) * K + k0 + cc * 8], &Asl[wb]);
            gl_lds16(&Bt[(size_t)(col0 + rr) * K + k0 + cc * 8], &Bsl[wb]);
        }
        __syncthreads();
#pragma unroll
        for (int h = 0; h < 2; h++) {
            const int sw = ((h * 4 + quad) ^ (l16 & 7)) * 8;
            bf16x8 af[4], bfr[4];
#pragma unroll
            for (int mt = 0; mt < 4; mt++)
                af[mt] = *(const bf16x8*)&Asl[(mh + mt * 16 + l16) * 64 + sw];
#pragma unroll
            for (int nt = 0; nt < 4; nt++)
                bfr[nt] = *(const bf16x8*)&Bsl[(nh + nt * 16 + l16) * 64 + sw];
#pragma unroll
            for (int mt = 0; mt < 4; mt++)
#pragma unroll
                for (int nt = 0; nt < 4; nt++)
                    acc[mt][nt] = MFMA16(af[mt], bfr[nt], acc[mt][nt]);
        }
        __syncthreads();
    }

    const float scl = (OBF && col0 < C_) ? SC_LOG2E : 1.f;
#pragma unroll
    for (int nt = 0; nt < 4; nt++) {
        int col = col0 + nh + nt * 16 + l16;
        float bv = bias[col];
#pragma unroll
        for (int mt = 0; mt < 4; mt++) {
            f32x4 v = acc[mt][nt];
#pragma unroll
            for (int r = 0; r < 4; r++) {
                int row = row0 + mh + mt * 16 + quad * 4 + r;
                if (OBF)
                    ((ushort*)outp)[(size_t)row * N + col] = f2bf((v[r] + bv) * scl);
                else
                    ((float*)outp)[(size_t)row * N + col] = v[r] + bv;
            }
        }
    }
}

// ---------- MFMA flash attention (round-6 measured-best body) ----------
__global__ __launch_bounds__(256) void attn_mfma(
    const ushort* __restrict__ qkvb, const ushort* __restrict__ Vt,
    ushort* __restrict__ attnb)
{
    __shared__ ushort Kd[2][64 * 64];     // [key][d], swizzled 16B chunks
    __shared__ ushort Vd[2][64 * 64];     // [d][key], swizzled 16B chunks
    __shared__ ushort Ptl[4 * 32 * 72];   // per-wave P^T [q][key], pad 72

    const int tid  = threadIdx.x;
    const int lane = tid & 63, w = tid >> 6;
    const int quad = lane >> 4, l16 = lane & 15;
    const int bh = blockIdx.y, b = bh / H_, h = bh % H_;
    const int q0 = blockIdx.x * 128 + w * 32;
    const size_t rowbase = (size_t)b * N_;
    const int hoff = h * D_;
    ushort* Ptw = Ptl + w * 32 * 72;
    const f32x4 Z4 = {0.f, 0.f, 0.f, 0.f};

    const ushort* Kg = qkvb + rowbase * (3 * C_) + C_ + hoff;  // + tok*(3C)
    const ushort* Vg = Vt + (size_t)bh * D_ * N_;              // + d*N_ + tok

    int rr0, cc0, rr1, cc1, wb0, wb1;
    {
        int c0 = w * 64 + lane, c1 = 256 + w * 64 + lane;
        rr0 = c0 >> 3; cc0 = (c0 & 7) ^ (rr0 & 7); wb0 = (w * 64) * 8;
        rr1 = c1 >> 3; cc1 = (c1 & 7) ^ (rr1 & 7); wb1 = (256 + w * 64) * 8;
    }
    const ushort* kp0 = Kg + (size_t)rr0 * (3 * C_) + cc0 * 8;
    const ushort* kp1 = Kg + (size_t)rr1 * (3 * C_) + cc1 * 8;
    const ushort* vp0 = Vg + (size_t)rr0 * N_ + cc0 * 8;
    const ushort* vp1 = Vg + (size_t)rr1 * N_ + cc1 * 8;

    bf16x8 Qf[2][2];
#pragma unroll
    for (int qt = 0; qt < 2; qt++)
#pragma unroll
        for (int c = 0; c < 2; c++)
            Qf[qt][c] = *(const bf16x8*)&qkvb[(rowbase + q0 + qt * 16 + l16) * (3 * C_)
                                              + hoff + c * 32 + quad * 8];

    f32x4 oacc[4][2];
#pragma unroll
    for (int dt = 0; dt < 4; dt++)
#pragma unroll
        for (int qt = 0; qt < 2; qt++) oacc[dt][qt] = (f32x4)0.f;
    float lrow[2] = {0.f, 0.f};

    gl_lds16(kp0, &Kd[0][wb0]);
    gl_lds16(vp0, &Vd[0][wb0]);
    gl_lds16(kp1, &Kd[0][wb1]);
    gl_lds16(vp1, &Vd[0][wb1]);
    kp0 += 64 * 3 * C_; kp1 += 64 * 3 * C_; vp0 += 64; vp1 += 64;
    __syncthreads();

#define TILE_BODY(CB, PREFETCH)                                               \
    {                                                                         \
        if (PREFETCH) {                                                       \
            gl_lds16(kp0, &Kd[(CB) ^ 1][wb0]);                                \
            gl_lds16(vp0, &Vd[(CB) ^ 1][wb0]);                                \
            gl_lds16(kp1, &Kd[(CB) ^ 1][wb1]);                                \
            gl_lds16(vp1, &Vd[(CB) ^ 1][wb1]);                                \
        }                                                                     \
        kp0 += 64 * 3 * C_; kp1 += 64 * 3 * C_; vp0 += 64; vp1 += 64;         \
        f32x4 sacc[4][2];                                                     \
        {   /* c = 0: MFMA with zero C operand */                             \
            bf16x8 kf[4];                                                     \
            _Pragma("unroll")                                                 \
            for (int kt = 0; kt < 4; kt++)                                    \
                kf[kt] = *(const bf16x8*)&Kd[CB][(kt * 16 + l16) * 64         \
                                               + ((quad) ^ (l16 & 7)) * 8];   \
            _Pragma("unroll")                                                 \
            for (int kt = 0; kt < 4; kt++)                                    \
                _Pragma("unroll")                                             \
                for (int qt = 0; qt < 2; qt++)                                \
                    sacc[kt][qt] = MFMA16(kf[kt], Qf[qt][0], Z4);             \
        }                                                                     \
        {   /* c = 1: accumulate */                                           \
            bf16x8 kf[4];                                                     \
            _Pragma("unroll")                                                 \
            for (int kt = 0; kt < 4; kt++)                                    \
                kf[kt] = *(const bf16x8*)&Kd[CB][(kt * 16 + l16) * 64         \
                                               + ((4 | quad) ^ (l16 & 7)) * 8]; \
            _Pragma("unroll")                                                 \
            for (int kt = 0; kt < 4; kt++)                                    \
                _Pragma("unroll")                                             \
                for (int qt = 0; qt < 2; qt++)                                \
                    sacc[kt][qt] = MFMA16(kf[kt], Qf[qt][1], sacc[kt][qt]);   \
        }                                                                     \
        _Pragma("unroll")                                                     \
        for (int qt = 0; qt < 2; qt++) {                                      \
            float sum = 0.f;                                                  \
            _Pragma("unroll")                                                 \
            for (int kt = 0; kt < 4; kt++) {                                  \
                float p0 = EXP2F(sacc[kt][qt][0]);                            \
                float p1 = EXP2F(sacc[kt][qt][1]);                            \
                float p2 = EXP2F(sacc[kt][qt][2]);                            \
                float p3 = EXP2F(sacc[kt][qt][3]);                            \
                sum += (p0 + p1) + (p2 + p3);                                 \
                uint2 pk;                                                     \
                pk.x = pack_bf2(p0, p1);                                      \
                pk.y = pack_bf2(p2, p3);                                      \
                *(uint2*)&Ptw[(qt * 16 + l16) * 72 + kt * 16 + quad * 4] = pk; \
            }                                                                 \
            lrow[qt] += sum;                                                  \
        }                                                                     \
        _Pragma("unroll")                                                     \
        for (int c = 0; c < 2; c++) {                                         \
            bf16x8 pf[2];                                                     \
            _Pragma("unroll")                                                 \
            for (int qt = 0; qt < 2; qt++)                                    \
                pf[qt] = *(const bf16x8*)&Ptw[(qt * 16 + l16) * 72            \
                                              + c * 32 + quad * 8];           \
            _Pragma("unroll")                                                 \
            for (int dt = 0; dt < 4; dt++) {                                  \
                bf16x8 vf = *(const bf16x8*)&Vd[CB][(dt * 16 + l16) * 64      \
                                   + (((c << 2) | quad) ^ (l16 & 7)) * 8];    \
                _Pragma("unroll")                                             \
                for (int qt = 0; qt < 2; qt++)                                \
                    oacc[dt][qt] = MFMA16(vf, pf[qt], oacc[dt][qt]);          \
            }                                                                 \
        }                                                                     \
        __syncthreads();                                                      \
    }

    for (int tt = 0; tt < 16; tt++) {
        TILE_BODY(0, 1)
        TILE_BODY(1, (tt < 15))
    }
#undef TILE_BODY

#pragma unroll
    for (int qt = 0; qt < 2; qt++) {
        float s = lrow[qt];
        s += __shfl_xor(s, 16, 64);
        s += __shfl_xor(s, 32, 64);
        float inv = 1.f / s;
        size_t orow = (rowbase + q0 + qt * 16 + l16) * C_ + hoff;
#pragma unroll
        for (int dt = 0; dt < 4; dt++) {
            union { ushort us[4]; unsigned long long u; } o;
#pragma unroll
            for (int r = 0; r < 4; r++) o.us[r] = f2bf(oacc[dt][qt][r] * inv);
            *(unsigned long long*)&attnb[orow + dt * 16 + quad * 4] = o.u;
        }
    }
}

// ---------------- launcher ----------------
extern "C" void kernel_launch(void* const* d_in, const int* in_sizes, int n_in,
                              void* d_out, int out_size, void* d_ws, size_t ws_size,
                              hipStream_t stream)
{
    const float* x     = (const float*)d_in[0];
    const float* Wqkv  = (const float*)d_in[1];
    const float* bqkv  = (const float*)d_in[2];
    const float* Wproj = (const float*)d_in[3];
    const float* bproj = (const float*)d_in[4];

    ushort* xb     = (ushort*)d_ws;                                    // [8192][768]
    ushort* Wqkvt  = xb + (size_t)B_ * N_ * C_;                        // [2304][768]
    ushort* Wprojt = Wqkvt + (size_t)3 * C_ * C_;                      // [768][768]
    ushort* qkvb   = Wprojt + (size_t)C_ * C_;                         // [8192][2304]
    ushort* attnb  = qkvb + (size_t)B_ * N_ * 3 * C_;                  // [8192][768]
    ushort* Vtb    = attnb + (size_t)B_ * N_ * C_;                     // [48][64][2048]

    const int M = B_ * N_;

    prep<<<5376, 256, 0, stream>>>(x, xb, Wqkv, Wqkvt, Wproj, Wprojt);

    gemm_bf16<true><<<dim3((3 * C_) / 128, M / 128), 256, 0, stream>>>(
        xb, Wqkvt, bqkv, qkvb, M, 3 * C_, C_);

    vtrans<<<dim3(N_ / 64, B_ * H_), 256, 0, stream>>>(qkvb, Vtb);

    attn_mfma<<<dim3(N_ / 128, B_ * H_), 256, 0, stream>>>(qkvb, Vtb, attnb);

    gemm_bf16<false><<<dim3(C_ / 128, M / 128), 256, 0, stream>>>(
        attnb, Wprojt, bproj, d_out, M, C_, C_);
}